// Round 10
// baseline (408.195 us; speedup 1.0000x reference)
//
#include <hip/hip_runtime.h>

typedef __bf16 bf16;
typedef __bf16 bf16x8 __attribute__((ext_vector_type(8)));
typedef __bf16 bf16x4 __attribute__((ext_vector_type(4)));
typedef float f32x4 __attribute__((ext_vector_type(4)));

#define NB 2
#define NQ 2048
#define NKK 2048
#define NC 512
#define NH 8
#define ND 64
#define NM (NB*NQ)   // 4096 rows
#define SPLITS 4
#define KSPL (NKK/SPLITS)   // 512 k per split
#define NTILES (KSPL/32)    // 16 chunks of 32 k
#define PLS 36              // proven 0-conflict stride

// ---------------- pass 0a: f32 -> bf16 ----------------
__global__ __launch_bounds__(256) void cvt_bf16_kernel(const float* __restrict__ in,
                                                       bf16* __restrict__ out, int n4) {
  int i = blockIdx.x * 256 + threadIdx.x;
  if (i < n4) {
    float4 v = ((const float4*)in)[i];
    bf16x4 o;
    o[0] = (bf16)v.x; o[1] = (bf16)v.y; o[2] = (bf16)v.z; o[3] = (bf16)v.w;
    ((bf16x4*)out)[i] = o;
  }
}

// ---------------- pass 0b: W[512][512] f32 -> WT[n][k] bf16 ----------------
__global__ __launch_bounds__(256) void transpose_w_kernel(const float* __restrict__ W,
                                                          bf16* __restrict__ WT) {
  __shared__ float t[32][33];
  int n0 = blockIdx.x * 32, k0 = blockIdx.y * 32;
  int c = threadIdx.x & 31, r0 = threadIdx.x >> 5;
  for (int r = r0; r < 32; r += 8) t[r][c] = W[(size_t)(k0 + r) * NC + n0 + c];
  __syncthreads();
  for (int r = r0; r < 32; r += 8) WT[(size_t)(n0 + r) * NC + k0 + c] = (bf16)t[c][r];
}

// ---------------- pass 1/3: GEMM  Y[M][512] = X[M][512] @ WT^T, fused epilogues ----------------
// epi: 0=Q (scale 1/8 -> qh[b][h][q][d])  1=K -> kh  2=V -> vh  3=G (sigmoid+bg -> f32)  4=O (+bo -> f32 d_out)
__global__ __launch_bounds__(256) void gemm_kernel(const bf16* __restrict__ X,
                                                   const bf16* __restrict__ WT,
                                                   const float* __restrict__ bias,
                                                   void* __restrict__ out, int epi) {
  __shared__ bf16 Xs[64][72];
  __shared__ bf16 Ws[64][72];
  int m0 = blockIdx.y * 64, n0 = blockIdx.x * 64;
  int tid = threadIdx.x, lane = tid & 63, wave = tid >> 6;
  int wm = wave >> 1, wn = wave & 1;
  int lr = lane & 15, lg = lane >> 4;
  f32x4 acc[2][2] = {};
  for (int k0 = 0; k0 < 512; k0 += 64) {
#pragma unroll
    for (int j = 0; j < 2; j++) {
      int cc = tid + 256 * j;
      int r = cc >> 3, c8 = (cc & 7) * 8;
      *(uint4*)&Xs[r][c8] = *(const uint4*)&X[(size_t)(m0 + r) * 512 + k0 + c8];
      *(uint4*)&Ws[r][c8] = *(const uint4*)&WT[(size_t)(n0 + r) * 512 + k0 + c8];
    }
    __syncthreads();
#pragma unroll
    for (int kk = 0; kk < 64; kk += 32) {
      bf16x8 a[2], b[2];
      a[0] = *(const bf16x8*)&Xs[wm * 32 + lr][kk + lg * 8];
      a[1] = *(const bf16x8*)&Xs[wm * 32 + 16 + lr][kk + lg * 8];
      b[0] = *(const bf16x8*)&Ws[wn * 32 + lr][kk + lg * 8];
      b[1] = *(const bf16x8*)&Ws[wn * 32 + 16 + lr][kk + lg * 8];
#pragma unroll
      for (int mi = 0; mi < 2; mi++)
#pragma unroll
        for (int ni = 0; ni < 2; ni++)
          acc[mi][ni] = __builtin_amdgcn_mfma_f32_16x16x32_bf16(a[mi], b[ni], acc[mi][ni], 0, 0, 0);
    }
    __syncthreads();
  }
#pragma unroll
  for (int mi = 0; mi < 2; mi++) {
#pragma unroll
    for (int ni = 0; ni < 2; ni++) {
#pragma unroll
      for (int i = 0; i < 4; i++) {
        int grow = m0 + wm * 32 + mi * 16 + lg * 4 + i;
        int gcol = n0 + wn * 32 + ni * 16 + lr;
        float v = acc[mi][ni][i];
        if (epi == 0) {
          int b = grow >> 11, q = grow & 2047, h = gcol >> 6, d = gcol & 63;
          ((bf16*)out)[((size_t)(b * NH + h) * NQ + q) * ND + d] = (bf16)(v * 0.125f);
        } else if (epi == 1 || epi == 2) {
          int b = grow >> 11, kq = grow & 2047, h = gcol >> 6, d = gcol & 63;
          ((bf16*)out)[((size_t)(b * NH + h) * NKK + kq) * ND + d] = (bf16)v;
        } else if (epi == 3) {
          v += bias[gcol];
          v = 1.0f / (1.0f + __expf(-v));
          ((float*)out)[(size_t)grow * 512 + gcol] = v;
        } else {
          ((float*)out)[(size_t)grow * 512 + gcol] = v + bias[gcol];
        }
      }
    }
  }
}

// ---------------- pass 1.5: vh[b][h][k][d] -> vT[b][h][d][k] ----------------
__global__ __launch_bounds__(256) void transpose_v_kernel(const bf16* __restrict__ vh,
                                                          bf16* __restrict__ vT) {
  __shared__ bf16 t[64][72];
  int bh = blockIdx.y;
  int kk0 = blockIdx.x * 64;
  const bf16* src = vh + (size_t)bh * NKK * ND;
  bf16* dst = vT + (size_t)bh * ND * NKK;
#pragma unroll
  for (int j = 0; j < 2; j++) {
    int c = threadIdx.x + 256 * j;
    int r = c >> 3, cc = (c & 7) * 8;
    *(uint4*)&t[r][cc] = *(const uint4*)&src[(size_t)(kk0 + r) * ND + cc];
  }
  __syncthreads();
#pragma unroll
  for (int j = 0; j < 2; j++) {
    int c = threadIdx.x + 256 * j;
    int d = c >> 3, ck = (c & 7) * 8;
    bf16 tmp[8];
#pragma unroll
    for (int x = 0; x < 8; x++) tmp[x] = t[ck + x][d];
    *(uint4*)&dst[(size_t)d * NKK + kk0 + ck] = *(const uint4*)tmp;
  }
}

// ---------------- global_load_lds helpers ----------------
__device__ __forceinline__ void gload16(const float* g, float* l) {
  __builtin_amdgcn_global_load_lds((const __attribute__((address_space(1))) void*)g,
                                   (__attribute__((address_space(3))) void*)l, 16, 0, 0);
}
__device__ __forceinline__ void gload4(const float* g, float* l) {
  __builtin_amdgcn_global_load_lds((const __attribute__((address_space(1))) void*)g,
                                   (__attribute__((address_space(3))) void*)l, 4, 0, 0);
}

// ---------------- pass 2: fused flash attention (counted-vmcnt pipeline) ----------------
// grid 1024 (XCD-swizzled): (q-tile, b, split); 8 waves = 8 heads.
// 3-slot bias LDS rotation, stage 1 chunk ahead; K/V reg ping-pong 1 ahead.
// Per half-iter: STAGE(t+1)[3 ops] ; LOADKV(t+1)[8 ops] ; s_waitcnt vmcnt(11)
// (newest window = 11 ops => stage(t) landed) ; raw s_barrier ; compute(t).
// Tail uniform via dummy re-stage/reload of the last chunk (keeps counts exact).
__global__ __launch_bounds__(512, 4) void attn_kernel(
    const bf16* __restrict__ qh, const bf16* __restrict__ kh, const bf16* __restrict__ vT,
    const float* __restrict__ bias1, const float* __restrict__ bias2,
    float* __restrict__ o_part, float* __restrict__ l_part) {
  __shared__ float b1s[3][16 * 32];        // 3 x 2 KB
  __shared__ float b2s[3][8 * 16 * 32];    // 3 x 16 KB
  __shared__ bf16 plds[8][16][PLS];        // 9 KB  -> total 63 KB => 2 WGs/CU
  int l = blockIdx.x;
  int idx = (l & 7) * 128 + (l >> 3);
  int q0 = (idx & 127) * 16;
  int r = idx >> 7;
  int b = r & 1, split = r >> 1;
  int tid = threadIdx.x;
  int h = tid >> 6, lane = tid & 63;
  int lr = lane & 15, lg = lane >> 4;
  int kbase = split * KSPL;
  const bf16* Qp = qh + ((size_t)(b * NH + h) * NQ + q0) * ND;
  const bf16* Kp = kh + (size_t)(b * NH + h) * NKK * ND + (size_t)kbase * ND;
  const bf16* Vt = vT + (size_t)(b * NH + h) * ND * NKK + kbase;

  bf16x8 qf0 = *(const bf16x8*)&Qp[lr * 64 + lg * 8];
  bf16x8 qf1 = *(const bf16x8*)&Qp[lr * 64 + 32 + lg * 8];

  f32x4 o[4] = {};
  float lrow[4] = {0.f, 0.f, 0.f, 0.f};
  bf16(*pl)[PLS] = plds[h];

#define STAGE(c, slot)                                                           \
  do {                                                                           \
    int kcol = kbase + (c) * 32;                                                 \
    _Pragma("unroll")                                                            \
    for (int j = 0; j < 2; j++) {                                                \
      int uu = tid + j * 512;                                                    \
      int h_ = uu >> 7, row_ = (uu >> 3) & 15, c4 = (uu & 7) * 4;                \
      gload16(bias2 + ((size_t)h_ * NQ + q0 + row_) * NKK + kcol + c4,           \
              &b2s[slot][uu * 4]);                                               \
    }                                                                            \
    int row1 = tid >> 5, col1 = tid & 31;                                        \
    gload4(bias1 + ((size_t)b * NQ + q0 + row1) * NKK + kcol + col1,             \
           &b1s[slot][tid]);                                                     \
  } while (0)

#define LOADKV(c, K0, K1, K2, K3, V0, V1, V2, V3)                                \
  do {                                                                           \
    const bf16* kp = Kp + (size_t)((c) * 32 + lr) * ND + lg * 8;                 \
    K0 = *(const bf16x8*)kp;                                                     \
    K1 = *(const bf16x8*)(kp + 32);                                              \
    K2 = *(const bf16x8*)(kp + 16 * ND);                                         \
    K3 = *(const bf16x8*)(kp + 16 * ND + 32);                                    \
    V0 = *(const bf16x8*)&Vt[(size_t)(0 * 16 + lr) * NKK + (c) * 32 + lg * 8];   \
    V1 = *(const bf16x8*)&Vt[(size_t)(1 * 16 + lr) * NKK + (c) * 32 + lg * 8];   \
    V2 = *(const bf16x8*)&Vt[(size_t)(2 * 16 + lr) * NKK + (c) * 32 + lg * 8];   \
    V3 = *(const bf16x8*)&Vt[(size_t)(3 * 16 + lr) * NKK + (c) * 32 + lg * 8];   \
  } while (0)

#define WAIT_BARRIER()                                                           \
  do {                                                                           \
    asm volatile("s_waitcnt vmcnt(11)" ::: "memory");                            \
    __builtin_amdgcn_s_barrier();                                                \
    asm volatile("" ::: "memory");                                               \
  } while (0)

#define COMPUTE(slot, K0, K1, K2, K3, V0, V1, V2, V3)                            \
  do {                                                                           \
    f32x4 sv0, sv1;                                                              \
    {                                                                            \
      f32x4 c;                                                                   \
      _Pragma("unroll")                                                          \
      for (int i = 0; i < 4; i++) {                                              \
        int off = (lg * 4 + i) * 32 + lr;                                        \
        c[i] = b1s[slot][off] + b2s[slot][h * 512 + off];                        \
      }                                                                          \
      c = __builtin_amdgcn_mfma_f32_16x16x32_bf16(qf0, K0, c, 0, 0, 0);          \
      c = __builtin_amdgcn_mfma_f32_16x16x32_bf16(qf1, K1, c, 0, 0, 0);          \
      sv0 = c;                                                                   \
    }                                                                            \
    {                                                                            \
      f32x4 c;                                                                   \
      _Pragma("unroll")                                                          \
      for (int i = 0; i < 4; i++) {                                              \
        int off = (lg * 4 + i) * 32 + 16 + lr;                                   \
        c[i] = b1s[slot][off] + b2s[slot][h * 512 + off];                        \
      }                                                                          \
      c = __builtin_amdgcn_mfma_f32_16x16x32_bf16(qf0, K2, c, 0, 0, 0);          \
      c = __builtin_amdgcn_mfma_f32_16x16x32_bf16(qf1, K3, c, 0, 0, 0);          \
      sv1 = c;                                                                   \
    }                                                                            \
    _Pragma("unroll")                                                            \
    for (int i = 0; i < 4; i++) {                                                \
      float p0 = __expf(sv0[i]);                                                 \
      float p1 = __expf(sv1[i]);                                                 \
      lrow[i] += p0 + p1;                                                        \
      pl[lg * 4 + i][lr] = (bf16)p0;                                             \
      pl[lg * 4 + i][16 + lr] = (bf16)p1;                                        \
    }                                                                            \
    bf16x8 pa = *(const bf16x8*)&pl[lr][lg * 8];                                 \
    o[0] = __builtin_amdgcn_mfma_f32_16x16x32_bf16(pa, V0, o[0], 0, 0, 0);       \
    o[1] = __builtin_amdgcn_mfma_f32_16x16x32_bf16(pa, V1, o[1], 0, 0, 0);       \
    o[2] = __builtin_amdgcn_mfma_f32_16x16x32_bf16(pa, V2, o[2], 0, 0, 0);       \
    o[3] = __builtin_amdgcn_mfma_f32_16x16x32_bf16(pa, V3, o[3], 0, 0, 0);       \
  } while (0)

  bf16x8 kA0, kA1, kA2, kA3, vA0, vA1, vA2, vA3;
  bf16x8 kB0, kB1, kB2, kB3, vB0, vB1, vB2, vB3;

  STAGE(0, 0);
  LOADKV(0, kA0, kA1, kA2, kA3, vA0, vA1, vA2, vA3);

  for (int t = 0; t < NTILES; t += 2) {
    int n1 = (t + 1 < NTILES) ? t + 1 : NTILES - 1;
    int n2 = (t + 2 < NTILES) ? t + 2 : NTILES - 1;
    STAGE(n1, (t + 1) % 3);
    LOADKV(n1, kB0, kB1, kB2, kB3, vB0, vB1, vB2, vB3);
    WAIT_BARRIER();
    COMPUTE(t % 3, kA0, kA1, kA2, kA3, vA0, vA1, vA2, vA3);
    STAGE(n2, (t + 2) % 3);
    LOADKV(n2, kA0, kA1, kA2, kA3, vA0, vA1, vA2, vA3);
    WAIT_BARRIER();
    COMPUTE((t + 1) % 3, kB0, kB1, kB2, kB3, vB0, vB1, vB2, vB3);
  }
#undef STAGE
#undef LOADKV
#undef WAIT_BARRIER
#undef COMPUTE

  // final row-sum reduce over the 16 lanes holding this row's columns (lr bits only)
  float lred[4];
#pragma unroll
  for (int i = 0; i < 4; i++) {
    float L = lrow[i];
    L += __shfl_xor(L, 1);
    L += __shfl_xor(L, 2);
    L += __shfl_xor(L, 4);
    L += __shfl_xor(L, 8);
    lred[i] = L;
  }

  float* op = o_part + (((size_t)(split * NB + b) * NH + h) * NQ + q0) * ND;
#pragma unroll
  for (int ni = 0; ni < 4; ni++)
#pragma unroll
    for (int i = 0; i < 4; i++)
      op[(lg * 4 + i) * ND + ni * 16 + lr] = o[ni][i];
  if (lr == 0) {
    float* lp = l_part + ((size_t)(split * NB + b) * NH + h) * NQ + q0;
#pragma unroll
    for (int i = 0; i < 4; i++) lp[lg * 4 + i] = lred[i];
  }
}

// ---------------- pass 2b: combine splits, gate, -> bf16 ----------------
__global__ __launch_bounds__(256) void combine_kernel(const float* __restrict__ o_part,
                                                      const float* __restrict__ l_part,
                                                      const float* __restrict__ gate,
                                                      bf16* __restrict__ ao) {
  size_t t = (size_t)blockIdx.x * 256 + threadIdx.x;  // over B*Q*H*16
  int d0 = (int)(t & 15) * 4;
  int h = (int)((t >> 4) & 7);
  int q = (int)((t >> 7) & 2047);
  int b = (int)(t >> 18);
  f32x4 acc = {};
  float L = 0.f;
#pragma unroll
  for (int s = 0; s < SPLITS; s++) {
    size_t base = (((size_t)(s * NB + b) * NH + h) * NQ + q);
    acc += *(const f32x4*)&o_part[base * ND + d0];
    L += l_part[base];
  }
  float inv = 1.0f / L;
  size_t gi = ((size_t)b * NQ + q) * 512 + h * 64 + d0;
  f32x4 g = *(const f32x4*)&gate[gi];
  bf16x4 r;
#pragma unroll
  for (int j = 0; j < 4; j++) r[j] = (bf16)(acc[j] * inv * g[j]);
  *(bf16x4*)&ao[gi] = r;
}

// ---------------- host launch ----------------
extern "C" void kernel_launch(void* const* d_in, const int* in_sizes, int n_in,
                              void* d_out, int out_size, void* d_ws, size_t ws_size,
                              hipStream_t stream) {
  const float* query = (const float*)d_in[0];
  const float* keyd  = (const float*)d_in[1];
  const float* bias1 = (const float*)d_in[2];
  const float* bias2 = (const float*)d_in[3];
  const float* wq = (const float*)d_in[4];
  const float* wk = (const float*)d_in[5];
  const float* wv = (const float*)d_in[6];
  const float* wo = (const float*)d_in[7];
  const float* bo = (const float*)d_in[8];
  const float* wg = (const float*)d_in[9];
  const float* bg = (const float*)d_in[10];

  char* ws = (char*)d_ws;
  size_t off = 0;
  auto alloc = [&](size_t bytes) {
    void* p = ws + off;
    off += (bytes + 255) & ~(size_t)255;
    return p;
  };
  bf16* qd_bf = (bf16*)alloc((size_t)NM * 512 * 2);
  bf16* kd_bf = (bf16*)alloc((size_t)NM * 512 * 2);
  bf16* wqT = (bf16*)alloc((size_t)512 * 512 * 2);
  bf16* wkT = (bf16*)alloc((size_t)512 * 512 * 2);
  bf16* wvT = (bf16*)alloc((size_t)512 * 512 * 2);
  bf16* wgT = (bf16*)alloc((size_t)512 * 512 * 2);
  bf16* woT = (bf16*)alloc((size_t)512 * 512 * 2);
  bf16* qh  = (bf16*)alloc((size_t)NB * NH * NQ * ND * 2);
  bf16* kh  = (bf16*)alloc((size_t)NB * NH * NKK * ND * 2);
  bf16* vh  = (bf16*)alloc((size_t)NB * NH * NKK * ND * 2);
  bf16* vTt = (bf16*)alloc((size_t)NB * NH * ND * NKK * 2);
  float* gbuf = (float*)alloc((size_t)NM * 512 * 4);
  bf16* aob = (bf16*)alloc((size_t)NM * 512 * 2);
  float* o_part = (float*)alloc((size_t)SPLITS * NB * NH * NQ * ND * 4);
  float* l_part = (float*)alloc((size_t)SPLITS * NB * NH * NQ * 4);

  int n4 = NM * 512 / 4;
  cvt_bf16_kernel<<<dim3(n4 / 256), 256, 0, stream>>>(query, qd_bf, n4);
  cvt_bf16_kernel<<<dim3(n4 / 256), 256, 0, stream>>>(keyd, kd_bf, n4);

  transpose_w_kernel<<<dim3(16, 16), 256, 0, stream>>>(wq, wqT);
  transpose_w_kernel<<<dim3(16, 16), 256, 0, stream>>>(wk, wkT);
  transpose_w_kernel<<<dim3(16, 16), 256, 0, stream>>>(wv, wvT);
  transpose_w_kernel<<<dim3(16, 16), 256, 0, stream>>>(wg, wgT);
  transpose_w_kernel<<<dim3(16, 16), 256, 0, stream>>>(wo, woT);

  gemm_kernel<<<dim3(8, 64), 256, 0, stream>>>(qd_bf, wqT, nullptr, qh, 0);
  gemm_kernel<<<dim3(8, 64), 256, 0, stream>>>(kd_bf, wkT, nullptr, kh, 1);
  gemm_kernel<<<dim3(8, 64), 256, 0, stream>>>(kd_bf, wvT, nullptr, vh, 2);
  gemm_kernel<<<dim3(8, 64), 256, 0, stream>>>(qd_bf, wgT, bg, gbuf, 3);

  transpose_v_kernel<<<dim3(32, 16), 256, 0, stream>>>(vh, vTt);

  attn_kernel<<<dim3(1024), 512, 0, stream>>>(qh, kh, vTt, bias1, bias2, o_part, l_part);

  combine_kernel<<<dim3((NB * NQ * NH * 16) / 256), 256, 0, stream>>>(o_part, l_part, gbuf, aob);

  gemm_kernel<<<dim3(8, 64), 256, 0, stream>>>(aob, woT, bo, d_out, 4);
}

// Round 11
// 307.279 us; speedup vs baseline: 1.3284x; 1.3284x over previous
//
#include <hip/hip_runtime.h>

typedef __bf16 bf16;
typedef __bf16 bf16x8 __attribute__((ext_vector_type(8)));
typedef __bf16 bf16x4 __attribute__((ext_vector_type(4)));
typedef float f32x4 __attribute__((ext_vector_type(4)));

#define NB 2
#define NQ 2048
#define NKK 2048
#define NC 512
#define NH 8
#define ND 64
#define NM (NB*NQ)   // 4096 rows
#define SPLITS 4
#define KSPL (NKK/SPLITS)   // 512 k per split
#define CHK 16              // staging chunk (k columns)
#define NCH (KSPL/CHK)      // 32 chunks per split
#define PLS 36              // proven 0-conflict stride

// ---------------- pass 0a: f32 -> bf16 ----------------
__global__ __launch_bounds__(256) void cvt_bf16_kernel(const float* __restrict__ in,
                                                       bf16* __restrict__ out, int n4) {
  int i = blockIdx.x * 256 + threadIdx.x;
  if (i < n4) {
    float4 v = ((const float4*)in)[i];
    bf16x4 o;
    o[0] = (bf16)v.x; o[1] = (bf16)v.y; o[2] = (bf16)v.z; o[3] = (bf16)v.w;
    ((bf16x4*)out)[i] = o;
  }
}

// ---------------- pass 0b: W[512][512] f32 -> WT[n][k] bf16 ----------------
__global__ __launch_bounds__(256) void transpose_w_kernel(const float* __restrict__ W,
                                                          bf16* __restrict__ WT) {
  __shared__ float t[32][33];
  int n0 = blockIdx.x * 32, k0 = blockIdx.y * 32;
  int c = threadIdx.x & 31, r0 = threadIdx.x >> 5;
  for (int r = r0; r < 32; r += 8) t[r][c] = W[(size_t)(k0 + r) * NC + n0 + c];
  __syncthreads();
  for (int r = r0; r < 32; r += 8) WT[(size_t)(n0 + r) * NC + k0 + c] = (bf16)t[c][r];
}

// ---------------- pass 1/3: GEMM  Y[M][512] = X[M][512] @ WT^T, fused epilogues ----------------
// epi: 0=Q (scale 1/8 -> qh[b][h][q][d])  1=K -> kh  2=V -> vh  3=G (sigmoid+bg -> f32)  4=O (+bo -> f32 d_out)
__global__ __launch_bounds__(256) void gemm_kernel(const bf16* __restrict__ X,
                                                   const bf16* __restrict__ WT,
                                                   const float* __restrict__ bias,
                                                   void* __restrict__ out, int epi) {
  __shared__ bf16 Xs[64][72];
  __shared__ bf16 Ws[64][72];
  int m0 = blockIdx.y * 64, n0 = blockIdx.x * 64;
  int tid = threadIdx.x, lane = tid & 63, wave = tid >> 6;
  int wm = wave >> 1, wn = wave & 1;
  int lr = lane & 15, lg = lane >> 4;
  f32x4 acc[2][2] = {};
  for (int k0 = 0; k0 < 512; k0 += 64) {
#pragma unroll
    for (int j = 0; j < 2; j++) {
      int cc = tid + 256 * j;
      int r = cc >> 3, c8 = (cc & 7) * 8;
      *(uint4*)&Xs[r][c8] = *(const uint4*)&X[(size_t)(m0 + r) * 512 + k0 + c8];
      *(uint4*)&Ws[r][c8] = *(const uint4*)&WT[(size_t)(n0 + r) * 512 + k0 + c8];
    }
    __syncthreads();
#pragma unroll
    for (int kk = 0; kk < 64; kk += 32) {
      bf16x8 a[2], b[2];
      a[0] = *(const bf16x8*)&Xs[wm * 32 + lr][kk + lg * 8];
      a[1] = *(const bf16x8*)&Xs[wm * 32 + 16 + lr][kk + lg * 8];
      b[0] = *(const bf16x8*)&Ws[wn * 32 + lr][kk + lg * 8];
      b[1] = *(const bf16x8*)&Ws[wn * 32 + 16 + lr][kk + lg * 8];
#pragma unroll
      for (int mi = 0; mi < 2; mi++)
#pragma unroll
        for (int ni = 0; ni < 2; ni++)
          acc[mi][ni] = __builtin_amdgcn_mfma_f32_16x16x32_bf16(a[mi], b[ni], acc[mi][ni], 0, 0, 0);
    }
    __syncthreads();
  }
#pragma unroll
  for (int mi = 0; mi < 2; mi++) {
#pragma unroll
    for (int ni = 0; ni < 2; ni++) {
#pragma unroll
      for (int i = 0; i < 4; i++) {
        int grow = m0 + wm * 32 + mi * 16 + lg * 4 + i;
        int gcol = n0 + wn * 32 + ni * 16 + lr;
        float v = acc[mi][ni][i];
        if (epi == 0) {
          int b = grow >> 11, q = grow & 2047, h = gcol >> 6, d = gcol & 63;
          ((bf16*)out)[((size_t)(b * NH + h) * NQ + q) * ND + d] = (bf16)(v * 0.125f);
        } else if (epi == 1 || epi == 2) {
          int b = grow >> 11, kq = grow & 2047, h = gcol >> 6, d = gcol & 63;
          ((bf16*)out)[((size_t)(b * NH + h) * NKK + kq) * ND + d] = (bf16)v;
        } else if (epi == 3) {
          v += bias[gcol];
          v = 1.0f / (1.0f + __expf(-v));
          ((float*)out)[(size_t)grow * 512 + gcol] = v;
        } else {
          ((float*)out)[(size_t)grow * 512 + gcol] = v + bias[gcol];
        }
      }
    }
  }
}

// ---------------- pass 1.5: vh[b][h][k][d] -> vT[b][h][d][k] ----------------
__global__ __launch_bounds__(256) void transpose_v_kernel(const bf16* __restrict__ vh,
                                                          bf16* __restrict__ vT) {
  __shared__ bf16 t[64][72];
  int bh = blockIdx.y;
  int kk0 = blockIdx.x * 64;
  const bf16* src = vh + (size_t)bh * NKK * ND;
  bf16* dst = vT + (size_t)bh * ND * NKK;
#pragma unroll
  for (int j = 0; j < 2; j++) {
    int c = threadIdx.x + 256 * j;
    int r = c >> 3, cc = (c & 7) * 8;
    *(uint4*)&t[r][cc] = *(const uint4*)&src[(size_t)(kk0 + r) * ND + cc];
  }
  __syncthreads();
#pragma unroll
  for (int j = 0; j < 2; j++) {
    int c = threadIdx.x + 256 * j;
    int d = c >> 3, ck = (c & 7) * 8;
    bf16 tmp[8];
#pragma unroll
    for (int x = 0; x < 8; x++) tmp[x] = t[ck + x][d];
    *(uint4*)&dst[(size_t)d * NKK + kk0 + ck] = *(const uint4*)tmp;
  }
}

// ---------------- global_load_lds helpers ----------------
__device__ __forceinline__ void gload16(const float* g, float* l) {
  __builtin_amdgcn_global_load_lds((const __attribute__((address_space(1))) void*)g,
                                   (__attribute__((address_space(3))) void*)l, 16, 0, 0);
}
__device__ __forceinline__ void gload4(const float* g, float* l) {
  __builtin_amdgcn_global_load_lds((const __attribute__((address_space(1))) void*)g,
                                   (__attribute__((address_space(3))) void*)l, 4, 0, 0);
}

// ---------------- pass 2: fused flash attention (16-k LDS-staged bias, 4 WGs/CU) ----------------
// grid 1024 (XCD-swizzled): (q-tile, b, split); 8 waves = 8 heads.
// R9 structure with halved staging quantum: slot = 9 KB (b2 8KB + b1 1KB),
// LDS total 27 KB -> 4 WGs/CU (32 waves, full cap). QK per 16-k sub-chunk;
// PV as K=32 MFMA every 2nd sub-chunk (P halves collected in plds).
__global__ __launch_bounds__(512, 8) void attn_kernel(
    const bf16* __restrict__ qh, const bf16* __restrict__ kh, const bf16* __restrict__ vT,
    const float* __restrict__ bias1, const float* __restrict__ bias2,
    float* __restrict__ o_part, float* __restrict__ l_part) {
  __shared__ float b1s[2][16 * 16];        // 2 x 1 KB
  __shared__ float b2s[2][8 * 16 * 16];    // 2 x 8 KB
  __shared__ bf16 plds[8][16][PLS];        // 9 KB   -> total 27 KB
  int l = blockIdx.x;
  int idx = (l & 7) * 128 + (l >> 3);
  int q0 = (idx & 127) * 16;
  int r = idx >> 7;
  int b = r & 1, split = r >> 1;
  int tid = threadIdx.x;
  int h = tid >> 6, lane = tid & 63;
  int lr = lane & 15, lg = lane >> 4;
  int kbase = split * KSPL;
  const bf16* Qp = qh + ((size_t)(b * NH + h) * NQ + q0) * ND;
  const bf16* Kp = kh + (size_t)(b * NH + h) * NKK * ND + (size_t)kbase * ND;
  const bf16* Vt = vT + (size_t)(b * NH + h) * ND * NKK + kbase;

  bf16x8 qf0 = *(const bf16x8*)&Qp[lr * 64 + lg * 8];
  bf16x8 qf1 = *(const bf16x8*)&Qp[lr * 64 + 32 + lg * 8];

  f32x4 o[4] = {};
  float lrow[4] = {0.f, 0.f, 0.f, 0.f};
  bf16(*pl)[PLS] = plds[h];

  // per-thread staging sources: b2 = 512 x gload16 (8 KB), b1 = 256 x gload4 (1 KB)
  const float* b2src = bias2 + ((size_t)(tid >> 6) * NQ + q0 + ((tid & 63) >> 2)) * NKK +
                       kbase + (tid & 3) * 4;
  const float* b1src = bias1 + ((size_t)b * NQ + q0 + (tid >> 4)) * NKK + kbase + (tid & 15);

#define STAGE(c, s)                                   \
  do {                                                \
    gload16(b2src + (c) * CHK, &b2s[s][tid * 4]);     \
    if (tid < 256) gload4(b1src + (c) * CHK, &b1s[s][tid]); \
  } while (0)

  // QK + exp for one 16-k sub-chunk; P half written to plds at column base pc
#define SUBCHUNK(t, s, pc)                                                     \
  do {                                                                         \
    int k0 = (t) * CHK;                                                        \
    bf16x8 kf0 = *(const bf16x8*)&Kp[(size_t)(k0 + lr) * ND + lg * 8];         \
    bf16x8 kf1 = *(const bf16x8*)&Kp[(size_t)(k0 + lr) * ND + 32 + lg * 8];    \
    f32x4 c;                                                                   \
    _Pragma("unroll")                                                          \
    for (int i = 0; i < 4; i++) {                                              \
      int off = (lg * 4 + i) * 16 + lr;                                        \
      c[i] = b1s[s][off] + b2s[s][h * 256 + off];                              \
    }                                                                          \
    c = __builtin_amdgcn_mfma_f32_16x16x32_bf16(qf0, kf0, c, 0, 0, 0);         \
    c = __builtin_amdgcn_mfma_f32_16x16x32_bf16(qf1, kf1, c, 0, 0, 0);         \
    _Pragma("unroll")                                                          \
    for (int i = 0; i < 4; i++) {                                              \
      float p = __expf(c[i]);                                                  \
      lrow[i] += p;                                                            \
      pl[lg * 4 + i][(pc) + lr] = (bf16)p;                                     \
    }                                                                          \
  } while (0)

  STAGE(0, 0);
  __syncthreads();

  for (int t = 0; t < NCH; t += 2) {
    // sub A (chunk t, slot 0): stage chunk t+1 into slot 1
    STAGE(t + 1, 1);
    SUBCHUNK(t, 0, 0);
    __syncthreads();
    // sub B (chunk t+1, slot 1): stage chunk t+2 into slot 0; then PV over 32 k
    if (t + 2 < NCH) STAGE(t + 2, 0);
    SUBCHUNK(t + 1, 1, 16);
    {
      int kv0 = t * CHK;  // 32-k PV base
      bf16x8 vf0 = *(const bf16x8*)&Vt[(size_t)(0 * 16 + lr) * NKK + kv0 + lg * 8];
      bf16x8 vf1 = *(const bf16x8*)&Vt[(size_t)(1 * 16 + lr) * NKK + kv0 + lg * 8];
      bf16x8 vf2 = *(const bf16x8*)&Vt[(size_t)(2 * 16 + lr) * NKK + kv0 + lg * 8];
      bf16x8 vf3 = *(const bf16x8*)&Vt[(size_t)(3 * 16 + lr) * NKK + kv0 + lg * 8];
      bf16x8 pa = *(const bf16x8*)&pl[lr][lg * 8];
      o[0] = __builtin_amdgcn_mfma_f32_16x16x32_bf16(pa, vf0, o[0], 0, 0, 0);
      o[1] = __builtin_amdgcn_mfma_f32_16x16x32_bf16(pa, vf1, o[1], 0, 0, 0);
      o[2] = __builtin_amdgcn_mfma_f32_16x16x32_bf16(pa, vf2, o[2], 0, 0, 0);
      o[3] = __builtin_amdgcn_mfma_f32_16x16x32_bf16(pa, vf3, o[3], 0, 0, 0);
    }
    __syncthreads();
  }
#undef STAGE
#undef SUBCHUNK

  // final row-sum reduce over the 16 lanes holding this row's columns (lr bits only)
  float lred[4];
#pragma unroll
  for (int i = 0; i < 4; i++) {
    float L = lrow[i];
    L += __shfl_xor(L, 1);
    L += __shfl_xor(L, 2);
    L += __shfl_xor(L, 4);
    L += __shfl_xor(L, 8);
    lred[i] = L;
  }

  float* op = o_part + (((size_t)(split * NB + b) * NH + h) * NQ + q0) * ND;
#pragma unroll
  for (int ni = 0; ni < 4; ni++)
#pragma unroll
    for (int i = 0; i < 4; i++)
      op[(lg * 4 + i) * ND + ni * 16 + lr] = o[ni][i];
  if (lr == 0) {
    float* lp = l_part + ((size_t)(split * NB + b) * NH + h) * NQ + q0;
#pragma unroll
    for (int i = 0; i < 4; i++) lp[lg * 4 + i] = lred[i];
  }
}

// ---------------- pass 2b: combine splits, gate, -> bf16 ----------------
__global__ __launch_bounds__(256) void combine_kernel(const float* __restrict__ o_part,
                                                      const float* __restrict__ l_part,
                                                      const float* __restrict__ gate,
                                                      bf16* __restrict__ ao) {
  size_t t = (size_t)blockIdx.x * 256 + threadIdx.x;  // over B*Q*H*16
  int d0 = (int)(t & 15) * 4;
  int h = (int)((t >> 4) & 7);
  int q = (int)((t >> 7) & 2047);
  int b = (int)(t >> 18);
  f32x4 acc = {};
  float L = 0.f;
#pragma unroll
  for (int s = 0; s < SPLITS; s++) {
    size_t base = (((size_t)(s * NB + b) * NH + h) * NQ + q);
    acc += *(const f32x4*)&o_part[base * ND + d0];
    L += l_part[base];
  }
  float inv = 1.0f / L;
  size_t gi = ((size_t)b * NQ + q) * 512 + h * 64 + d0;
  f32x4 g = *(const f32x4*)&gate[gi];
  bf16x4 r;
#pragma unroll
  for (int j = 0; j < 4; j++) r[j] = (bf16)(acc[j] * inv * g[j]);
  *(bf16x4*)&ao[gi] = r;
}

// ---------------- host launch ----------------
extern "C" void kernel_launch(void* const* d_in, const int* in_sizes, int n_in,
                              void* d_out, int out_size, void* d_ws, size_t ws_size,
                              hipStream_t stream) {
  const float* query = (const float*)d_in[0];
  const float* keyd  = (const float*)d_in[1];
  const float* bias1 = (const float*)d_in[2];
  const float* bias2 = (const float*)d_in[3];
  const float* wq = (const float*)d_in[4];
  const float* wk = (const float*)d_in[5];
  const float* wv = (const float*)d_in[6];
  const float* wo = (const float*)d_in[7];
  const float* bo = (const float*)d_in[8];
  const float* wg = (const float*)d_in[9];
  const float* bg = (const float*)d_in[10];

  char* ws = (char*)d_ws;
  size_t off = 0;
  auto alloc = [&](size_t bytes) {
    void* p = ws + off;
    off += (bytes + 255) & ~(size_t)255;
    return p;
  };
  bf16* qd_bf = (bf16*)alloc((size_t)NM * 512 * 2);
  bf16* kd_bf = (bf16*)alloc((size_t)NM * 512 * 2);
  bf16* wqT = (bf16*)alloc((size_t)512 * 512 * 2);
  bf16* wkT = (bf16*)alloc((size_t)512 * 512 * 2);
  bf16* wvT = (bf16*)alloc((size_t)512 * 512 * 2);
  bf16* wgT = (bf16*)alloc((size_t)512 * 512 * 2);
  bf16* woT = (bf16*)alloc((size_t)512 * 512 * 2);
  bf16* qh  = (bf16*)alloc((size_t)NB * NH * NQ * ND * 2);
  bf16* kh  = (bf16*)alloc((size_t)NB * NH * NKK * ND * 2);
  bf16* vh  = (bf16*)alloc((size_t)NB * NH * NKK * ND * 2);
  bf16* vTt = (bf16*)alloc((size_t)NB * NH * ND * NKK * 2);
  float* gbuf = (float*)alloc((size_t)NM * 512 * 4);
  bf16* aob = (bf16*)alloc((size_t)NM * 512 * 2);
  float* o_part = (float*)alloc((size_t)SPLITS * NB * NH * NQ * ND * 4);
  float* l_part = (float*)alloc((size_t)SPLITS * NB * NH * NQ * 4);

  int n4 = NM * 512 / 4;
  cvt_bf16_kernel<<<dim3(n4 / 256), 256, 0, stream>>>(query, qd_bf, n4);
  cvt_bf16_kernel<<<dim3(n4 / 256), 256, 0, stream>>>(keyd, kd_bf, n4);

  transpose_w_kernel<<<dim3(16, 16), 256, 0, stream>>>(wq, wqT);
  transpose_w_kernel<<<dim3(16, 16), 256, 0, stream>>>(wk, wkT);
  transpose_w_kernel<<<dim3(16, 16), 256, 0, stream>>>(wv, wvT);
  transpose_w_kernel<<<dim3(16, 16), 256, 0, stream>>>(wg, wgT);
  transpose_w_kernel<<<dim3(16, 16), 256, 0, stream>>>(wo, woT);

  gemm_kernel<<<dim3(8, 64), 256, 0, stream>>>(qd_bf, wqT, nullptr, qh, 0);
  gemm_kernel<<<dim3(8, 64), 256, 0, stream>>>(kd_bf, wkT, nullptr, kh, 1);
  gemm_kernel<<<dim3(8, 64), 256, 0, stream>>>(kd_bf, wvT, nullptr, vh, 2);
  gemm_kernel<<<dim3(8, 64), 256, 0, stream>>>(qd_bf, wgT, bg, gbuf, 3);

  transpose_v_kernel<<<dim3(32, 16), 256, 0, stream>>>(vh, vTt);

  attn_kernel<<<dim3(1024), 512, 0, stream>>>(qh, kh, vTt, bias1, bias2, o_part, l_part);

  combine_kernel<<<dim3((NB * NQ * NH * 16) / 256), 256, 0, stream>>>(o_part, l_part, gbuf, aob);

  gemm_kernel<<<dim3(8, 64), 256, 0, stream>>>(aob, woT, bo, d_out, 4);
}

// Round 12
// 263.099 us; speedup vs baseline: 1.5515x; 1.1679x over previous
//
#include <hip/hip_runtime.h>

typedef __bf16 bf16;
typedef __bf16 bf16x8 __attribute__((ext_vector_type(8)));
typedef __bf16 bf16x4 __attribute__((ext_vector_type(4)));
typedef float f32x4 __attribute__((ext_vector_type(4)));

#define NB 2
#define NQ 2048
#define NKK 2048
#define NC 512
#define NH 8
#define ND 64
#define NM (NB*NQ)   // 4096 rows
#define SPLITS 4
#define KSPL (NKK/SPLITS)   // 512 k per split
#define NTILES (KSPL/32)    // 16 chunks of 32 k
#define PLS 36              // proven 0-conflict stride

// ---------------- pass 0a: f32 -> bf16 ----------------
__global__ __launch_bounds__(256) void cvt_bf16_kernel(const float* __restrict__ in,
                                                       bf16* __restrict__ out, int n4) {
  int i = blockIdx.x * 256 + threadIdx.x;
  if (i < n4) {
    float4 v = ((const float4*)in)[i];
    bf16x4 o;
    o[0] = (bf16)v.x; o[1] = (bf16)v.y; o[2] = (bf16)v.z; o[3] = (bf16)v.w;
    ((bf16x4*)out)[i] = o;
  }
}

// ---------------- pass 0b: W[512][512] f32 -> WT[n][k] bf16 ----------------
__global__ __launch_bounds__(256) void transpose_w_kernel(const float* __restrict__ W,
                                                          bf16* __restrict__ WT) {
  __shared__ float t[32][33];
  int n0 = blockIdx.x * 32, k0 = blockIdx.y * 32;
  int c = threadIdx.x & 31, r0 = threadIdx.x >> 5;
  for (int r = r0; r < 32; r += 8) t[r][c] = W[(size_t)(k0 + r) * NC + n0 + c];
  __syncthreads();
  for (int r = r0; r < 32; r += 8) WT[(size_t)(n0 + r) * NC + k0 + c] = (bf16)t[c][r];
}

// ---------------- pass 1/3: GEMM  Y[M][512] = X[M][512] @ WT^T, fused epilogues ----------------
// epi: 0=Q (scale 1/8 -> qh[b][h][q][d])  1=K -> kh  2=V -> vh  3=G (sigmoid+bg -> f32)  4=O (+bo -> f32 d_out)
__global__ __launch_bounds__(256) void gemm_kernel(const bf16* __restrict__ X,
                                                   const bf16* __restrict__ WT,
                                                   const float* __restrict__ bias,
                                                   void* __restrict__ out, int epi) {
  __shared__ bf16 Xs[64][72];
  __shared__ bf16 Ws[64][72];
  int m0 = blockIdx.y * 64, n0 = blockIdx.x * 64;
  int tid = threadIdx.x, lane = tid & 63, wave = tid >> 6;
  int wm = wave >> 1, wn = wave & 1;
  int lr = lane & 15, lg = lane >> 4;
  f32x4 acc[2][2] = {};
  for (int k0 = 0; k0 < 512; k0 += 64) {
#pragma unroll
    for (int j = 0; j < 2; j++) {
      int cc = tid + 256 * j;
      int r = cc >> 3, c8 = (cc & 7) * 8;
      *(uint4*)&Xs[r][c8] = *(const uint4*)&X[(size_t)(m0 + r) * 512 + k0 + c8];
      *(uint4*)&Ws[r][c8] = *(const uint4*)&WT[(size_t)(n0 + r) * 512 + k0 + c8];
    }
    __syncthreads();
#pragma unroll
    for (int kk = 0; kk < 64; kk += 32) {
      bf16x8 a[2], b[2];
      a[0] = *(const bf16x8*)&Xs[wm * 32 + lr][kk + lg * 8];
      a[1] = *(const bf16x8*)&Xs[wm * 32 + 16 + lr][kk + lg * 8];
      b[0] = *(const bf16x8*)&Ws[wn * 32 + lr][kk + lg * 8];
      b[1] = *(const bf16x8*)&Ws[wn * 32 + 16 + lr][kk + lg * 8];
#pragma unroll
      for (int mi = 0; mi < 2; mi++)
#pragma unroll
        for (int ni = 0; ni < 2; ni++)
          acc[mi][ni] = __builtin_amdgcn_mfma_f32_16x16x32_bf16(a[mi], b[ni], acc[mi][ni], 0, 0, 0);
    }
    __syncthreads();
  }
#pragma unroll
  for (int mi = 0; mi < 2; mi++) {
#pragma unroll
    for (int ni = 0; ni < 2; ni++) {
#pragma unroll
      for (int i = 0; i < 4; i++) {
        int grow = m0 + wm * 32 + mi * 16 + lg * 4 + i;
        int gcol = n0 + wn * 32 + ni * 16 + lr;
        float v = acc[mi][ni][i];
        if (epi == 0) {
          int b = grow >> 11, q = grow & 2047, h = gcol >> 6, d = gcol & 63;
          ((bf16*)out)[((size_t)(b * NH + h) * NQ + q) * ND + d] = (bf16)(v * 0.125f);
        } else if (epi == 1 || epi == 2) {
          int b = grow >> 11, kq = grow & 2047, h = gcol >> 6, d = gcol & 63;
          ((bf16*)out)[((size_t)(b * NH + h) * NKK + kq) * ND + d] = (bf16)v;
        } else if (epi == 3) {
          v += bias[gcol];
          v = 1.0f / (1.0f + __expf(-v));
          ((float*)out)[(size_t)grow * 512 + gcol] = v;
        } else {
          ((float*)out)[(size_t)grow * 512 + gcol] = v + bias[gcol];
        }
      }
    }
  }
}

// ---------------- pass 1.5: vh[b][h][k][d] -> vT[b][h][d][k] ----------------
__global__ __launch_bounds__(256) void transpose_v_kernel(const bf16* __restrict__ vh,
                                                          bf16* __restrict__ vT) {
  __shared__ bf16 t[64][72];
  int bh = blockIdx.y;
  int kk0 = blockIdx.x * 64;
  const bf16* src = vh + (size_t)bh * NKK * ND;
  bf16* dst = vT + (size_t)bh * ND * NKK;
#pragma unroll
  for (int j = 0; j < 2; j++) {
    int c = threadIdx.x + 256 * j;
    int r = c >> 3, cc = (c & 7) * 8;
    *(uint4*)&t[r][cc] = *(const uint4*)&src[(size_t)(kk0 + r) * ND + cc];
  }
  __syncthreads();
#pragma unroll
  for (int j = 0; j < 2; j++) {
    int c = threadIdx.x + 256 * j;
    int d = c >> 3, ck = (c & 7) * 8;
    bf16 tmp[8];
#pragma unroll
    for (int x = 0; x < 8; x++) tmp[x] = t[ck + x][d];
    *(uint4*)&dst[(size_t)d * NKK + kk0 + ck] = *(const uint4*)tmp;
  }
}

// ---------------- global_load_lds helper ----------------
__device__ __forceinline__ void gload16(const float* g, float* l) {
  __builtin_amdgcn_global_load_lds((const __attribute__((address_space(1))) void*)g,
                                   (__attribute__((address_space(3))) void*)l, 16, 0, 0);
}

// swizzled read: LDS[row][colgrp^ (row&7)][col&3] holds global [row][col]
__device__ __forceinline__ float bread(const float* base, int row, int col) {
  return base[row * 32 + ((((col >> 2) ^ (row & 7)) << 2) | (col & 3))];
}

// ---------------- pass 2: fused flash attention (barrier-free wave-private staging) ----------------
// grid 1024 (XCD-swizzled): (q-tile, b, split); 8 waves = 8 heads.
// Each wave double-buffers ITS OWN bias1/bias2 chunk (4KB) in private LDS slots via
// global_load_lds, one chunk ahead, with NO __syncthreads in the loop: per-wave
// vmcnt ordering only. Stalls of the 16 resident waves are independent/staggered.
// Global source is XOR-pre-swizzled (16B granularity) so scalar bias reads are 2-way.
__global__ __launch_bounds__(512, 4) void attn_kernel(
    const bf16* __restrict__ qh, const bf16* __restrict__ kh, const bf16* __restrict__ vT,
    const float* __restrict__ bias1, const float* __restrict__ bias2,
    float* __restrict__ o_part, float* __restrict__ l_part) {
  __shared__ float b1w[8][2][512];         // 32 KB: per-wave bias1 chunk slots
  __shared__ float b2w[8][2][512];         // 32 KB: per-wave bias2 chunk slots
  __shared__ bf16 plds[8][16][PLS];        //  9 KB -> total ~73 KB => 2 WGs/CU
  int l = blockIdx.x;
  int idx = (l & 7) * 128 + (l >> 3);
  int q0 = (idx & 127) * 16;
  int r = idx >> 7;
  int b = r & 1, split = r >> 1;
  int tid = threadIdx.x;
  int h = tid >> 6, lane = tid & 63;
  int lr = lane & 15, lg = lane >> 4;
  int kbase = split * KSPL;
  const bf16* Qp = qh + ((size_t)(b * NH + h) * NQ + q0) * ND;
  const bf16* Kp = kh + (size_t)(b * NH + h) * NKK * ND + (size_t)kbase * ND;
  const bf16* Vt = vT + (size_t)(b * NH + h) * ND * NKK + kbase;

  // per-lane staging source offsets (XOR-swizzled col group; row&7 == lane>>3 for both ops)
  int srow = lane >> 3;                        // rows srow (op0) and srow+8 (op1)
  int scolg = ((lane & 7) ^ (lane >> 3)) * 4;  // swizzled 4-col group
  const float* b1base = bias1 + ((size_t)b * NQ + q0) * NKK + kbase + scolg;
  const float* b2base = bias2 + ((size_t)h * NQ + q0) * NKK + kbase + scolg;

  bf16x8 qf0 = *(const bf16x8*)&Qp[lr * 64 + lg * 8];
  bf16x8 qf1 = *(const bf16x8*)&Qp[lr * 64 + 32 + lg * 8];

  f32x4 o[4] = {};
  float lrow[4] = {0.f, 0.f, 0.f, 0.f};
  bf16(*pl)[PLS] = plds[h];

  // stage one 32-k chunk's bias1+bias2 for THIS wave into private slot s (4 gload16/lane-wave)
#define STAGE(c, s)                                                              \
  do {                                                                           \
    int kc = (c) * 32;                                                           \
    gload16(b1base + (size_t)srow * NKK + kc, &b1w[h][s][0]);                    \
    gload16(b1base + (size_t)(srow + 8) * NKK + kc, &b1w[h][s][256]);            \
    gload16(b2base + (size_t)srow * NKK + kc, &b2w[h][s][0]);                    \
    gload16(b2base + (size_t)(srow + 8) * NKK + kc, &b2w[h][s][256]);            \
  } while (0)

#define COMPUTE(t, s)                                                            \
  do {                                                                           \
    int k0 = (t) * 32;                                                           \
    bf16x8 vf0 = *(const bf16x8*)&Vt[(size_t)(0 * 16 + lr) * NKK + k0 + lg * 8]; \
    bf16x8 vf1 = *(const bf16x8*)&Vt[(size_t)(1 * 16 + lr) * NKK + k0 + lg * 8]; \
    bf16x8 vf2 = *(const bf16x8*)&Vt[(size_t)(2 * 16 + lr) * NKK + k0 + lg * 8]; \
    bf16x8 vf3 = *(const bf16x8*)&Vt[(size_t)(3 * 16 + lr) * NKK + k0 + lg * 8]; \
    f32x4 sv[2];                                                                 \
    _Pragma("unroll")                                                            \
    for (int f = 0; f < 2; f++) {                                                \
      const bf16* kp = Kp + (size_t)(k0 + f * 16 + lr) * ND + lg * 8;            \
      bf16x8 kfa = *(const bf16x8*)kp;                                           \
      bf16x8 kfb = *(const bf16x8*)(kp + 32);                                    \
      f32x4 c;                                                                   \
      _Pragma("unroll")                                                          \
      for (int i = 0; i < 4; i++) {                                              \
        int row = lg * 4 + i, col = f * 16 + lr;                                 \
        c[i] = bread(&b1w[h][s][0], row, col) + bread(&b2w[h][s][0], row, col);  \
      }                                                                          \
      c = __builtin_amdgcn_mfma_f32_16x16x32_bf16(qf0, kfa, c, 0, 0, 0);         \
      c = __builtin_amdgcn_mfma_f32_16x16x32_bf16(qf1, kfb, c, 0, 0, 0);         \
      sv[f] = c;                                                                 \
    }                                                                            \
    _Pragma("unroll")                                                            \
    for (int i = 0; i < 4; i++) {                                                \
      float p0 = __expf(sv[0][i]);                                               \
      float p1 = __expf(sv[1][i]);                                               \
      lrow[i] += p0 + p1;                                                        \
      pl[lg * 4 + i][lr] = (bf16)p0;                                             \
      pl[lg * 4 + i][16 + lr] = (bf16)p1;                                        \
    }                                                                            \
    bf16x8 pa = *(const bf16x8*)&pl[lr][lg * 8];                                 \
    o[0] = __builtin_amdgcn_mfma_f32_16x16x32_bf16(pa, vf0, o[0], 0, 0, 0);      \
    o[1] = __builtin_amdgcn_mfma_f32_16x16x32_bf16(pa, vf1, o[1], 0, 0, 0);      \
    o[2] = __builtin_amdgcn_mfma_f32_16x16x32_bf16(pa, vf2, o[2], 0, 0, 0);      \
    o[3] = __builtin_amdgcn_mfma_f32_16x16x32_bf16(pa, vf3, o[3], 0, 0, 0);      \
  } while (0)

  STAGE(0, 0);
#pragma unroll 1
  for (int t = 0; t < NTILES; t += 2) {
    STAGE(t + 1, 1);
    COMPUTE(t, 0);
    if (t + 2 < NTILES) STAGE(t + 2, 0);
    COMPUTE(t + 1, 1);
  }
#undef STAGE
#undef COMPUTE

  // final row-sum reduce over the 16 lanes holding this row's columns (lr bits only)
  float lred[4];
#pragma unroll
  for (int i = 0; i < 4; i++) {
    float L = lrow[i];
    L += __shfl_xor(L, 1);
    L += __shfl_xor(L, 2);
    L += __shfl_xor(L, 4);
    L += __shfl_xor(L, 8);
    lred[i] = L;
  }

  float* op = o_part + (((size_t)(split * NB + b) * NH + h) * NQ + q0) * ND;
#pragma unroll
  for (int ni = 0; ni < 4; ni++)
#pragma unroll
    for (int i = 0; i < 4; i++)
      op[(lg * 4 + i) * ND + ni * 16 + lr] = o[ni][i];
  if (lr == 0) {
    float* lp = l_part + ((size_t)(split * NB + b) * NH + h) * NQ + q0;
#pragma unroll
    for (int i = 0; i < 4; i++) lp[lg * 4 + i] = lred[i];
  }
}

// ---------------- pass 2b: combine splits, gate, -> bf16 ----------------
__global__ __launch_bounds__(256) void combine_kernel(const float* __restrict__ o_part,
                                                      const float* __restrict__ l_part,
                                                      const float* __restrict__ gate,
                                                      bf16* __restrict__ ao) {
  size_t t = (size_t)blockIdx.x * 256 + threadIdx.x;  // over B*Q*H*16
  int d0 = (int)(t & 15) * 4;
  int h = (int)((t >> 4) & 7);
  int q = (int)((t >> 7) & 2047);
  int b = (int)(t >> 18);
  f32x4 acc = {};
  float L = 0.f;
#pragma unroll
  for (int s = 0; s < SPLITS; s++) {
    size_t base = (((size_t)(s * NB + b) * NH + h) * NQ + q);
    acc += *(const f32x4*)&o_part[base * ND + d0];
    L += l_part[base];
  }
  float inv = 1.0f / L;
  size_t gi = ((size_t)b * NQ + q) * 512 + h * 64 + d0;
  f32x4 g = *(const f32x4*)&gate[gi];
  bf16x4 r;
#pragma unroll
  for (int j = 0; j < 4; j++) r[j] = (bf16)(acc[j] * inv * g[j]);
  *(bf16x4*)&ao[gi] = r;
}

// ---------------- host launch ----------------
extern "C" void kernel_launch(void* const* d_in, const int* in_sizes, int n_in,
                              void* d_out, int out_size, void* d_ws, size_t ws_size,
                              hipStream_t stream) {
  const float* query = (const float*)d_in[0];
  const float* keyd  = (const float*)d_in[1];
  const float* bias1 = (const float*)d_in[2];
  const float* bias2 = (const float*)d_in[3];
  const float* wq = (const float*)d_in[4];
  const float* wk = (const float*)d_in[5];
  const float* wv = (const float*)d_in[6];
  const float* wo = (const float*)d_in[7];
  const float* bo = (const float*)d_in[8];
  const float* wg = (const float*)d_in[9];
  const float* bg = (const float*)d_in[10];

  char* ws = (char*)d_ws;
  size_t off = 0;
  auto alloc = [&](size_t bytes) {
    void* p = ws + off;
    off += (bytes + 255) & ~(size_t)255;
    return p;
  };
  bf16* qd_bf = (bf16*)alloc((size_t)NM * 512 * 2);
  bf16* kd_bf = (bf16*)alloc((size_t)NM * 512 * 2);
  bf16* wqT = (bf16*)alloc((size_t)512 * 512 * 2);
  bf16* wkT = (bf16*)alloc((size_t)512 * 512 * 2);
  bf16* wvT = (bf16*)alloc((size_t)512 * 512 * 2);
  bf16* wgT = (bf16*)alloc((size_t)512 * 512 * 2);
  bf16* woT = (bf16*)alloc((size_t)512 * 512 * 2);
  bf16* qh  = (bf16*)alloc((size_t)NB * NH * NQ * ND * 2);
  bf16* kh  = (bf16*)alloc((size_t)NB * NH * NKK * ND * 2);
  bf16* vh  = (bf16*)alloc((size_t)NB * NH * NKK * ND * 2);
  bf16* vTt = (bf16*)alloc((size_t)NB * NH * ND * NKK * 2);
  float* gbuf = (float*)alloc((size_t)NM * 512 * 4);
  bf16* aob = (bf16*)alloc((size_t)NM * 512 * 2);
  float* o_part = (float*)alloc((size_t)SPLITS * NB * NH * NQ * ND * 4);
  float* l_part = (float*)alloc((size_t)SPLITS * NB * NH * NQ * 4);

  int n4 = NM * 512 / 4;
  cvt_bf16_kernel<<<dim3(n4 / 256), 256, 0, stream>>>(query, qd_bf, n4);
  cvt_bf16_kernel<<<dim3(n4 / 256), 256, 0, stream>>>(keyd, kd_bf, n4);

  transpose_w_kernel<<<dim3(16, 16), 256, 0, stream>>>(wq, wqT);
  transpose_w_kernel<<<dim3(16, 16), 256, 0, stream>>>(wk, wkT);
  transpose_w_kernel<<<dim3(16, 16), 256, 0, stream>>>(wv, wvT);
  transpose_w_kernel<<<dim3(16, 16), 256, 0, stream>>>(wg, wgT);
  transpose_w_kernel<<<dim3(16, 16), 256, 0, stream>>>(wo, woT);

  gemm_kernel<<<dim3(8, 64), 256, 0, stream>>>(qd_bf, wqT, nullptr, qh, 0);
  gemm_kernel<<<dim3(8, 64), 256, 0, stream>>>(kd_bf, wkT, nullptr, kh, 1);
  gemm_kernel<<<dim3(8, 64), 256, 0, stream>>>(kd_bf, wvT, nullptr, vh, 2);
  gemm_kernel<<<dim3(8, 64), 256, 0, stream>>>(qd_bf, wgT, bg, gbuf, 3);

  transpose_v_kernel<<<dim3(32, 16), 256, 0, stream>>>(vh, vTt);

  attn_kernel<<<dim3(1024), 512, 0, stream>>>(qh, kh, vTt, bias1, bias2, o_part, l_part);

  combine_kernel<<<dim3((NB * NQ * NH * 16) / 256), 256, 0, stream>>>(o_part, l_part, gbuf, aob);

  gemm_kernel<<<dim3(8, 64), 256, 0, stream>>>(aob, woT, bo, d_out, 4);
}